// Round 9
// baseline (2065.087 us; speedup 1.0000x reference)
//
#include <hip/hip_runtime.h>

// ---------------------------------------------------------------------------
// MutualRec forward: 5x GATv2 + ChebConv(k=3) + mutualistic MLP + edge dots
// R9: GEMM X-path moved from scalar loads (readfirstlane -> s_load, shared
//     lgkmcnt with W ds_reads, SGPR-capped pipelining) to per-lane float4
//     vector loads (vmcnt path, deep pipelining). W stays in LDS.
//     Fusions (proj_k, dual128_k), CSR GAT/cheb, edge-list dots unchanged.
// ---------------------------------------------------------------------------

#define LRELU_SLOPE 0.2f
#define GEMM_BLOCKS 2048
#define DUAL_BLOCKS 1024
#define EDGE_BLOCKS 2048

// Load 16 consecutive floats of row xr starting at kc into xa[0..15] (VGPRs).
__device__ __forceinline__ void ld16(const float* __restrict__ xr, int kc, float* xa) {
  const float4 t0 = *(const float4*)(xr + kc + 0);
  const float4 t1 = *(const float4*)(xr + kc + 4);
  const float4 t2 = *(const float4*)(xr + kc + 8);
  const float4 t3 = *(const float4*)(xr + kc + 12);
  xa[0] = t0.x; xa[1] = t0.y; xa[2] = t0.z; xa[3] = t0.w;
  xa[4] = t1.x; xa[5] = t1.y; xa[6] = t1.z; xa[7] = t1.w;
  xa[8] = t2.x; xa[9] = t2.y; xa[10] = t2.z; xa[11] = t2.w;
  xa[12] = t3.x; xa[13] = t3.y; xa[14] = t3.z; xa[15] = t3.w;
}

// ============================ GEMM family ==================================
// Y[N,64] = sum_m X_m[N,64] @ W[m] + b ; W is [NMAT*64,64] row-major stacked.
template <int NMAT>
__global__ void gemm_multi_k(const float* __restrict__ X0,
                             const float* __restrict__ X1,
                             const float* __restrict__ X2,
                             const float* __restrict__ W,
                             const float* __restrict__ b,
                             float* __restrict__ Y, int N) {
  __shared__ float Ws[NMAT * 4096];
  for (int i = threadIdx.x; i < NMAT * 4096; i += 256) Ws[i] = W[i];
  __syncthreads();
  const int lane = threadIdx.x & 63;
  const int gw = (blockIdx.x * 256 + threadIdx.x) >> 6;
  const int nw = (gridDim.x * 256) >> 6;
  const float bj = b[lane];
  for (int r0 = gw * 4; r0 < N; r0 += nw * 4) {
    const int r1 = (r0 + 1 < N) ? r0 + 1 : r0;
    const int r2 = (r0 + 2 < N) ? r0 + 2 : r0;
    const int r3 = (r0 + 3 < N) ? r0 + 3 : r0;
    float y0 = bj, y1 = bj, y2 = bj, y3 = bj;
#pragma unroll
    for (int m = 0; m < NMAT; ++m) {
      const float* Xm = (m == 0) ? X0 : ((m == 1) ? X1 : X2);
      const float* xr0 = Xm + (size_t)r0 * 64;
      const float* xr1 = Xm + (size_t)r1 * 64;
      const float* xr2 = Xm + (size_t)r2 * 64;
      const float* xr3 = Xm + (size_t)r3 * 64;
      const float* wm = Ws + m * 4096;
#pragma unroll 1
      for (int kc = 0; kc < 64; kc += 16) {
        float xa[16], xb[16], xc[16], xd[16];
        ld16(xr0, kc, xa); ld16(xr1, kc, xb);
        ld16(xr2, kc, xc); ld16(xr3, kc, xd);
#pragma unroll
        for (int kk = 0; kk < 16; ++kk) {
          const float w = wm[(kc + kk) * 64 + lane];
          y0 = fmaf(xa[kk], w, y0);
          y1 = fmaf(xb[kk], w, y1);
          y2 = fmaf(xc[kk], w, y2);
          y3 = fmaf(xd[kk], w, y3);
        }
      }
    }
    Y[(size_t)r0 * 64 + lane] = y0;
    if (r0 + 1 < N) Y[(size_t)(r0 + 1) * 64 + lane] = y1;
    if (r0 + 2 < N) Y[(size_t)(r0 + 2) * 64 + lane] = y2;
    if (r0 + 3 < N) Y[(size_t)(r0 + 3) * 64 + lane] = y3;
  }
}

// ---- proj_k<NP>: Y_p = X @ W_p + b_p. One X stream, NP outputs. ----
template <int NP>
__global__ void proj_k(const float* __restrict__ X,
                       const float* __restrict__ W0, const float* __restrict__ W1,
                       const float* __restrict__ W2, const float* __restrict__ W3,
                       const float* __restrict__ b0, const float* __restrict__ b1,
                       const float* __restrict__ b2, const float* __restrict__ b3,
                       float* __restrict__ Y0, float* __restrict__ Y1,
                       float* __restrict__ Y2, float* __restrict__ Y3, int N) {
  __shared__ float Ws[NP * 4096];
#pragma unroll
  for (int p = 0; p < NP; ++p) {
    const float* Wp = (p == 0) ? W0 : ((p == 1) ? W1 : ((p == 2) ? W2 : W3));
    for (int i = threadIdx.x; i < 4096; i += 256) Ws[p * 4096 + i] = Wp[i];
  }
  __syncthreads();
  const int lane = threadIdx.x & 63;
  const int gw = (blockIdx.x * 256 + threadIdx.x) >> 6;
  const int nw = (gridDim.x * 256) >> 6;
  float bj[NP];
#pragma unroll
  for (int p = 0; p < NP; ++p) {
    const float* bp = (p == 0) ? b0 : ((p == 1) ? b1 : ((p == 2) ? b2 : b3));
    bj[p] = bp[lane];
  }
  for (int r0 = gw * 4; r0 < N; r0 += nw * 4) {
    const int r1 = (r0 + 1 < N) ? r0 + 1 : r0;
    const int r2 = (r0 + 2 < N) ? r0 + 2 : r0;
    const int r3 = (r0 + 3 < N) ? r0 + 3 : r0;
    const float* xr0 = X + (size_t)r0 * 64;
    const float* xr1 = X + (size_t)r1 * 64;
    const float* xr2 = X + (size_t)r2 * 64;
    const float* xr3 = X + (size_t)r3 * 64;
    float y[NP][4];
#pragma unroll
    for (int p = 0; p < NP; ++p) {
      y[p][0] = bj[p]; y[p][1] = bj[p]; y[p][2] = bj[p]; y[p][3] = bj[p];
    }
#pragma unroll 1
    for (int kc = 0; kc < 64; kc += 16) {
      float xa[16], xb[16], xc[16], xd[16];
      ld16(xr0, kc, xa); ld16(xr1, kc, xb);
      ld16(xr2, kc, xc); ld16(xr3, kc, xd);
#pragma unroll
      for (int kk = 0; kk < 16; ++kk) {
#pragma unroll
        for (int p = 0; p < NP; ++p) {
          const float w = Ws[p * 4096 + (kc + kk) * 64 + lane];
          y[p][0] = fmaf(xa[kk], w, y[p][0]);
          y[p][1] = fmaf(xb[kk], w, y[p][1]);
          y[p][2] = fmaf(xc[kk], w, y[p][2]);
          y[p][3] = fmaf(xd[kk], w, y[p][3]);
        }
      }
    }
#pragma unroll
    for (int p = 0; p < NP; ++p) {
      float* Yp = (p == 0) ? Y0 : ((p == 1) ? Y1 : ((p == 2) ? Y2 : Y3));
      Yp[(size_t)r0 * 64 + lane] = y[p][0];
      if (r0 + 1 < N) Yp[(size_t)(r0 + 1) * 64 + lane] = y[p][1];
      if (r0 + 2 < N) Yp[(size_t)(r0 + 2) * 64 + lane] = y[p][2];
      if (r0 + 3 < N) Yp[(size_t)(r0 + 3) * 64 + lane] = y[p][3];
    }
  }
}

// ---- dual128_k<SHARED>: Y0=[A0,C0]@W0+b0 ; Y1=[A1,C1]@W1+b1 (W: [128,64]).
template <bool SHARED>
__global__ void dual128_k(const float* __restrict__ A0, const float* __restrict__ C0,
                          const float* __restrict__ A1, const float* __restrict__ C1,
                          const float* __restrict__ W0, const float* __restrict__ W1,
                          const float* __restrict__ b0, const float* __restrict__ b1,
                          float* __restrict__ Y0, float* __restrict__ Y1, int N) {
  __shared__ float Ws[2 * 8192];
  for (int i = threadIdx.x; i < 8192; i += 256) Ws[i] = W0[i];
  for (int i = threadIdx.x; i < 8192; i += 256) Ws[8192 + i] = W1[i];
  __syncthreads();
  const int lane = threadIdx.x & 63;
  const int gw = (blockIdx.x * 256 + threadIdx.x) >> 6;
  const int nw = (gridDim.x * 256) >> 6;
  const float bj0 = b0[lane], bj1 = b1[lane];
  for (int r0 = gw * 4; r0 < N; r0 += nw * 4) {
    const int r1 = (r0 + 1 < N) ? r0 + 1 : r0;
    const int r2 = (r0 + 2 < N) ? r0 + 2 : r0;
    const int r3 = (r0 + 3 < N) ? r0 + 3 : r0;
    float ya[4] = {bj0, bj0, bj0, bj0};
    float yb[4] = {bj1, bj1, bj1, bj1};
    // phase A0 -> ya  (W0 rows 0..63)
    {
      const float* p0 = A0 + (size_t)r0 * 64;
      const float* p1 = A0 + (size_t)r1 * 64;
      const float* p2 = A0 + (size_t)r2 * 64;
      const float* p3 = A0 + (size_t)r3 * 64;
#pragma unroll 1
      for (int kc = 0; kc < 64; kc += 16) {
        float xa[16], xb[16], xc[16], xd[16];
        ld16(p0, kc, xa); ld16(p1, kc, xb); ld16(p2, kc, xc); ld16(p3, kc, xd);
#pragma unroll
        for (int kk = 0; kk < 16; ++kk) {
          const float w = Ws[(kc + kk) * 64 + lane];
          ya[0] = fmaf(xa[kk], w, ya[0]);
          ya[1] = fmaf(xb[kk], w, ya[1]);
          ya[2] = fmaf(xc[kk], w, ya[2]);
          ya[3] = fmaf(xd[kk], w, ya[3]);
        }
      }
    }
    // phase A1 -> yb  (W1 rows 0..63)
    {
      const float* p0 = A1 + (size_t)r0 * 64;
      const float* p1 = A1 + (size_t)r1 * 64;
      const float* p2 = A1 + (size_t)r2 * 64;
      const float* p3 = A1 + (size_t)r3 * 64;
#pragma unroll 1
      for (int kc = 0; kc < 64; kc += 16) {
        float xa[16], xb[16], xc[16], xd[16];
        ld16(p0, kc, xa); ld16(p1, kc, xb); ld16(p2, kc, xc); ld16(p3, kc, xd);
#pragma unroll
        for (int kk = 0; kk < 16; ++kk) {
          const float w = Ws[8192 + (kc + kk) * 64 + lane];
          yb[0] = fmaf(xa[kk], w, yb[0]);
          yb[1] = fmaf(xb[kk], w, yb[1]);
          yb[2] = fmaf(xc[kk], w, yb[2]);
          yb[3] = fmaf(xd[kk], w, yb[3]);
        }
      }
    }
    if (SHARED) {
      const float* p0 = C0 + (size_t)r0 * 64;
      const float* p1 = C0 + (size_t)r1 * 64;
      const float* p2 = C0 + (size_t)r2 * 64;
      const float* p3 = C0 + (size_t)r3 * 64;
#pragma unroll 1
      for (int kc = 0; kc < 64; kc += 16) {
        float xa[16], xb[16], xc[16], xd[16];
        ld16(p0, kc, xa); ld16(p1, kc, xb); ld16(p2, kc, xc); ld16(p3, kc, xd);
#pragma unroll
        for (int kk = 0; kk < 16; ++kk) {
          const float wA = Ws[(64 + kc + kk) * 64 + lane];
          const float wB = Ws[8192 + (64 + kc + kk) * 64 + lane];
          ya[0] = fmaf(xa[kk], wA, ya[0]); yb[0] = fmaf(xa[kk], wB, yb[0]);
          ya[1] = fmaf(xb[kk], wA, ya[1]); yb[1] = fmaf(xb[kk], wB, yb[1]);
          ya[2] = fmaf(xc[kk], wA, ya[2]); yb[2] = fmaf(xc[kk], wB, yb[2]);
          ya[3] = fmaf(xd[kk], wA, ya[3]); yb[3] = fmaf(xd[kk], wB, yb[3]);
        }
      }
    } else {
      {
        const float* p0 = C0 + (size_t)r0 * 64;
        const float* p1 = C0 + (size_t)r1 * 64;
        const float* p2 = C0 + (size_t)r2 * 64;
        const float* p3 = C0 + (size_t)r3 * 64;
#pragma unroll 1
        for (int kc = 0; kc < 64; kc += 16) {
          float xa[16], xb[16], xc[16], xd[16];
          ld16(p0, kc, xa); ld16(p1, kc, xb); ld16(p2, kc, xc); ld16(p3, kc, xd);
#pragma unroll
          for (int kk = 0; kk < 16; ++kk) {
            const float w = Ws[(64 + kc + kk) * 64 + lane];
            ya[0] = fmaf(xa[kk], w, ya[0]);
            ya[1] = fmaf(xb[kk], w, ya[1]);
            ya[2] = fmaf(xc[kk], w, ya[2]);
            ya[3] = fmaf(xd[kk], w, ya[3]);
          }
        }
      }
      {
        const float* p0 = C1 + (size_t)r0 * 64;
        const float* p1 = C1 + (size_t)r1 * 64;
        const float* p2 = C1 + (size_t)r2 * 64;
        const float* p3 = C1 + (size_t)r3 * 64;
#pragma unroll 1
        for (int kc = 0; kc < 64; kc += 16) {
          float xa[16], xb[16], xc[16], xd[16];
          ld16(p0, kc, xa); ld16(p1, kc, xb); ld16(p2, kc, xc); ld16(p3, kc, xd);
#pragma unroll
          for (int kk = 0; kk < 16; ++kk) {
            const float w = Ws[8192 + (64 + kc + kk) * 64 + lane];
            yb[0] = fmaf(xa[kk], w, yb[0]);
            yb[1] = fmaf(xb[kk], w, yb[1]);
            yb[2] = fmaf(xc[kk], w, yb[2]);
            yb[3] = fmaf(xd[kk], w, yb[3]);
          }
        }
      }
    }
    Y0[(size_t)r0 * 64 + lane] = ya[0];
    Y1[(size_t)r0 * 64 + lane] = yb[0];
    if (r0 + 1 < N) { Y0[(size_t)(r0 + 1) * 64 + lane] = ya[1]; Y1[(size_t)(r0 + 1) * 64 + lane] = yb[1]; }
    if (r0 + 2 < N) { Y0[(size_t)(r0 + 2) * 64 + lane] = ya[2]; Y1[(size_t)(r0 + 2) * 64 + lane] = yb[2]; }
    if (r0 + 3 < N) { Y0[(size_t)(r0 + 3) * 64 + lane] = ya[3]; Y1[(size_t)(r0 + 3) * 64 + lane] = yb[3]; }
  }
}

// ========================= CSR build (counting sort) =======================
__global__ void hist_k(const int* __restrict__ key, int* __restrict__ cnt, int E) {
  const int e = blockIdx.x * blockDim.x + threadIdx.x;
  if (e < E) atomicAdd(cnt + key[e], 1);
}

__global__ void scan1_k(const int* __restrict__ in, int* __restrict__ out,
                        int* __restrict__ bsum, int n) {
  __shared__ int tmp[256];
  const int t = threadIdx.x;
  const int base = blockIdx.x * 1024 + t * 4;
  int v0 = (base + 0 < n) ? in[base + 0] : 0;
  int v1 = (base + 1 < n) ? in[base + 1] : 0;
  int v2 = (base + 2 < n) ? in[base + 2] : 0;
  int v3 = (base + 3 < n) ? in[base + 3] : 0;
  const int s = v0 + v1 + v2 + v3;
  tmp[t] = s;
  __syncthreads();
  for (int off = 1; off < 256; off <<= 1) {
    const int x = (t >= off) ? tmp[t - off] : 0;
    __syncthreads();
    tmp[t] += x;
    __syncthreads();
  }
  const int excl = tmp[t] - s;
  if (t == 255) bsum[blockIdx.x] = tmp[255];
  if (base + 0 < n) out[base + 0] = excl;
  if (base + 1 < n) out[base + 1] = excl + v0;
  if (base + 2 < n) out[base + 2] = excl + v0 + v1;
  if (base + 3 < n) out[base + 3] = excl + v0 + v1 + v2;
}
__global__ void scan2_k(int* __restrict__ bsum, int nb) {
  if (threadIdx.x == 0) {
    int acc = 0;
    for (int i = 0; i < nb; ++i) { const int v = bsum[i]; bsum[i] = acc; acc += v; }
  }
}
__global__ void scan3_k(int* __restrict__ out, const int* __restrict__ bsum, int n) {
  const int i = blockIdx.x * blockDim.x + threadIdx.x;
  if (i < n) out[i] += bsum[i >> 10];
}

__global__ void scatter_k(const int* __restrict__ key, const int* __restrict__ other,
                          int* __restrict__ cursor, int* __restrict__ srt, int E) {
  const int e = blockIdx.x * blockDim.x + threadIdx.x;
  if (e < E) {
    const int p = atomicAdd(cursor + key[e], 1);
    srt[p] = other[e];
  }
}

// ======================= CSR-based graph kernels ===========================
__global__ void gat_csr_k(const float* __restrict__ fs, const float* __restrict__ fd,
                          const float* __restrict__ attn,
                          const int* __restrict__ rowptr, const int* __restrict__ nbr,
                          float* __restrict__ out, int N) {
  const int lane = threadIdx.x & 63;
  const int wid = (blockIdx.x * blockDim.x + threadIdx.x) >> 6;
  const int nw = (gridDim.x * blockDim.x) >> 6;
  const float aw = attn[lane];
  for (int n = wid; n < N; n += nw) {
    const int beg = rowptr[n], end = rowptr[n + 1];
    const float fdv = fd[(size_t)n * 64 + lane];
    float acc = 0.0f, den = 0.0f;
    int e = beg;
    for (; e + 1 < end; e += 2) {
      const int s0 = nbr[e], s1 = nbr[e + 1];
      const float f0 = fs[(size_t)s0 * 64 + lane];
      const float f1 = fs[(size_t)s1 * 64 + lane];
      float v0 = f0 + fdv; v0 = v0 > 0.0f ? v0 : LRELU_SLOPE * v0;
      float v1 = f1 + fdv; v1 = v1 > 0.0f ? v1 : LRELU_SLOPE * v1;
      float p0 = v0 * aw, p1 = v1 * aw;
#pragma unroll
      for (int o = 32; o; o >>= 1) {
        p0 += __shfl_xor(p0, o, 64);
        p1 += __shfl_xor(p1, o, 64);
      }
      const float e0 = __expf(p0), e1 = __expf(p1);
      den += e0 + e1;
      acc = fmaf(e0, f0, acc);
      acc = fmaf(e1, f1, acc);
    }
    if (e < end) {
      const int s0 = nbr[e];
      const float f0 = fs[(size_t)s0 * 64 + lane];
      float v0 = f0 + fdv; v0 = v0 > 0.0f ? v0 : LRELU_SLOPE * v0;
      float p0 = v0 * aw;
#pragma unroll
      for (int o = 32; o; o >>= 1) p0 += __shfl_xor(p0, o, 64);
      const float e0 = __expf(p0);
      den += e0;
      acc = fmaf(e0, f0, acc);
    }
    const float inv = den > 0.0f ? 1.0f / den : 0.0f;
    out[(size_t)n * 64 + lane] = acc * inv;
  }
}

// Fused Cheb step (MODE 1: T1; MODE 2: T2)
template <int MODE>
__global__ void cheb_csr_k(const float* __restrict__ x, const float* __restrict__ T0,
                           const float* __restrict__ Tp, const float* __restrict__ dinv,
                           const float* __restrict__ lam,
                           const int* __restrict__ rowptr, const int* __restrict__ nbr,
                           float* __restrict__ outT, int N) {
  const float re = 2.0f / lam[0];
  const int lane = threadIdx.x & 63;
  const int wid = (blockIdx.x * blockDim.x + threadIdx.x) >> 6;
  const int nw = (gridDim.x * blockDim.x) >> 6;
  for (int n = wid; n < N; n += nw) {
    const int beg = rowptr[n], end = rowptr[n + 1];
    float acc = 0.0f;
    int e = beg;
    for (; e + 1 < end; e += 2) {
      const int s0 = nbr[e], s1 = nbr[e + 1];
      acc = fmaf(x[(size_t)s0 * 64 + lane], dinv[s0], acc);
      acc = fmaf(x[(size_t)s1 * 64 + lane], dinv[s1], acc);
    }
    if (e < end) {
      const int s0 = nbr[e];
      acc = fmaf(x[(size_t)s0 * 64 + lane], dinv[s0], acc);
    }
    const float hv = acc * dinv[n];
    float r;
    if (MODE == 1) {
      r = -re * hv + (re - 1.0f) * T0[(size_t)n * 64 + lane];
    } else {
      r = -2.0f * re * hv + 2.0f * (re - 1.0f) * Tp[(size_t)n * 64 + lane]
          - T0[(size_t)n * 64 + lane];
    }
    outT[(size_t)n * 64 + lane] = r;
  }
}

__global__ void dinv_k(const int* __restrict__ rowptr, float* __restrict__ dinv, int N) {
  const int i = blockIdx.x * blockDim.x + threadIdx.x;
  if (i < N) {
    const float deg = (float)(rowptr[i + 1] - rowptr[i]);
    dinv[i] = rsqrtf(fmaxf(deg, 1.0f));
  }
}

// ---- mutualistic ----
__global__ void mut_k(const float* __restrict__ hP, const float* __restrict__ hS,
                      float* __restrict__ mP, float* __restrict__ mS, int N) {
  const int lane = threadIdx.x & 63;
  const int u = (blockIdx.x * blockDim.x + threadIdx.x) >> 6;
  if (u >= N) return;
  const float p = hP[(size_t)u * 64 + lane];
  const float s = hS[(size_t)u * 64 + lane];
  const float m = p * s;
  float mxp = p, mxs = s;
#pragma unroll
  for (int o = 32; o; o >>= 1) {
    mxp = fmaxf(mxp, __shfl_xor(mxp, o, 64));
    mxs = fmaxf(mxs, __shfl_xor(mxs, o, 64));
  }
  const float ep = __expf(p - mxp);
  const float es = __expf(s - mxs);
  float sp = ep, ss = es;
#pragma unroll
  for (int o = 32; o; o >>= 1) {
    sp += __shfl_xor(sp, o, 64);
    ss += __shfl_xor(ss, o, 64);
  }
  mP[(size_t)u * 64 + lane] = m * (ep / sp);
  mS[(size_t)u * 64 + lane] = m * (es / ss);
}

// ---- edge dot (edge-list, ILP-2) ----
__global__ void dot_k(const float* __restrict__ A, const float* __restrict__ Bm,
                      const int* __restrict__ src, const int* __restrict__ dst,
                      float* __restrict__ out, int E) {
  const int lane = threadIdx.x & 63;
  const int wid = (blockIdx.x * blockDim.x + threadIdx.x) >> 6;
  const int nw = (gridDim.x * blockDim.x) >> 6;
  for (int e0 = wid * 2; e0 < E; e0 += nw * 2) {
    const bool has1 = (e0 + 1 < E);
    const int s0 = src[e0], d0 = dst[e0];
    const int s1 = has1 ? src[e0 + 1] : s0;
    const int d1 = has1 ? dst[e0 + 1] : d0;
    float p0 = A[(size_t)s0 * 64 + lane] * Bm[(size_t)d0 * 64 + lane];
    float p1 = A[(size_t)s1 * 64 + lane] * Bm[(size_t)d1 * 64 + lane];
#pragma unroll
    for (int o = 32; o; o >>= 1) {
      p0 += __shfl_xor(p0, o, 64);
      p1 += __shfl_xor(p1, o, 64);
    }
    if (lane == 0) {
      out[e0] = p0;
      if (has1) out[e0 + 1] = p1;
    }
  }
}

// ---------------------------------------------------------------------------

static void build_csr(const int* key, const int* other, int E, int N,
                      int* rowptr, int* srt, int* cursor, int* bsum,
                      hipStream_t stream) {
  const int n1 = N + 1;
  hipMemsetAsync(cursor, 0, (size_t)n1 * 4, stream);
  hist_k<<<(E + 255) / 256, 256, 0, stream>>>(key, cursor, E);
  const int nb = (n1 + 1023) / 1024;
  scan1_k<<<nb, 256, 0, stream>>>(cursor, rowptr, bsum, n1);
  scan2_k<<<1, 64, 0, stream>>>(bsum, nb);
  scan3_k<<<(n1 + 255) / 256, 256, 0, stream>>>(rowptr, bsum, n1);
  hipMemcpyAsync(cursor, rowptr, (size_t)N * 4, hipMemcpyDeviceToDevice, stream);
  scatter_k<<<(E + 255) / 256, 256, 0, stream>>>(key, other, cursor, srt, E);
}

extern "C" void kernel_launch(void* const* d_in, const int* in_sizes, int n_in,
                              void* d_out, int out_size, void* d_ws, size_t ws_size,
                              hipStream_t stream) {
  const float* user_emb = (const float*)d_in[0];
  const float* item_emb = (const float*)d_in[1];
  const int* rate_src = (const int*)d_in[2];
  const int* rate_dst = (const int*)d_in[3];
  const int* link_src = (const int*)d_in[4];
  const int* link_dst = (const int*)d_in[5];
  const int* neg_rate_src = (const int*)d_in[6];
  const int* neg_rate_dst = (const int*)d_in[7];
  const int* neg_link_src = (const int*)d_in[8];
  const int* neg_link_dst = (const int*)d_in[9];
  const float* lam = (const float*)d_in[10];
  const float* gat_Wsrc = (const float*)d_in[11];
  const float* gat_bsrc = (const float*)d_in[12];
  const float* gat_Wdst = (const float*)d_in[13];
  const float* gat_bdst = (const float*)d_in[14];
  const float* gat_attn = (const float*)d_in[15];
  const float* W_out = (const float*)d_in[16];
  const float* b_out = (const float*)d_in[17];
  const float* cheb_W = (const float*)d_in[18];
  const float* cheb_b = (const float*)d_in[19];
  const float* Wc = (const float*)d_in[20];
  const float* bc = (const float*)d_in[21];
  const float* Wsm = (const float*)d_in[22];
  const float* bs = (const float*)d_in[23];
  const float* WpP = (const float*)d_in[24];
  const float* bpP = (const float*)d_in[25];
  const float* WpS = (const float*)d_in[26];
  const float* bpS = (const float*)d_in[27];

  const int NU = in_sizes[0] / 64;
  const int NI = in_sizes[1] / 64;
  const int NR = in_sizes[2];
  const int NL = in_sizes[4];
  const int NMAX = NU > NI ? NU : NI;
  const size_t MAT = (size_t)NMAX * 64;

  float* ws = (float*)d_ws;
  float* B0 = ws + 0 * MAT;
  float* B1 = ws + 1 * MAT;
  float* B2 = ws + 2 * MAT;
  float* B3 = ws + 3 * MAT;
  float* B4 = ws + 4 * MAT;
  float* B5 = ws + 5 * MAT;
  float* B6 = ws + 6 * MAT;
  float* B7 = ws + 7 * MAT;
  int* ip = (int*)(ws + 8 * MAT);
  int* rp_rd = ip;                   // NI+1
  int* rp_rs = rp_rd + (NI + 1);     // NU+1
  int* rp_ld = rp_rs + (NU + 1);     // NU+1
  int* srt_rd = rp_ld + (NU + 1);    // NR
  int* srt_rs = srt_rd + NR;         // NR
  int* srt_ld = srt_rs + NR;         // NL
  int* cursor = srt_ld + NL;         // NMAX+1
  int* bsum = cursor + (NMAX + 1);   // 256
  float* dinv = (float*)(bsum + 256);  // NU

  const int W64 = 64 * 64, B64 = 64;

  // ---- 3 CSR groupings ----
  build_csr(rate_dst, rate_src, NR, NI, rp_rd, srt_rd, cursor, bsum, stream);
  build_csr(rate_src, rate_dst, NR, NU, rp_rs, srt_rs, cursor, bsum, stream);
  build_csr(link_dst, link_src, NL, NU, rp_ld, srt_ld, cursor, bsum, stream);

  // ---- user projections (4-in-1): fs0->B0, fd1->B1, fd2->B2, fd3->B3 ----
  proj_k<4><<<GEMM_BLOCKS, 256, 0, stream>>>(
      user_emb,
      gat_Wsrc + 0 * W64, gat_Wdst + 1 * W64, gat_Wdst + 2 * W64, gat_Wdst + 3 * W64,
      gat_bsrc + 0 * B64, gat_bdst + 1 * B64, gat_bdst + 2 * B64, gat_bdst + 3 * B64,
      B0, B1, B2, B3, NU);
  // ---- item projections (2-in-1): fd0->B4, fs1->B5 ----
  proj_k<2><<<GEMM_BLOCKS, 256, 0, stream>>>(
      item_emb,
      gat_Wdst + 0 * W64, gat_Wsrc + 1 * W64, nullptr, nullptr,
      gat_bdst + 0 * B64, gat_bsrc + 1 * B64, nullptr, nullptr,
      B4, B5, nullptr, nullptr, NI);

  // ---- gat0: (fs=B0, fd=B4) over rate-by-item -> B6 (h1_item) ----
  gat_csr_k<<<EDGE_BLOCKS, 256, 0, stream>>>(B0, B4, gat_attn + 0 * B64, rp_rd, srt_rd, B6, NI);
  // ---- gat1: (fs=B5, fd=B1) over rate-by-user -> B7 (h2_user) ----
  gat_csr_k<<<EDGE_BLOCKS, 256, 0, stream>>>(B5, B1, gat_attn + 1 * B64, rp_rs, srt_rs, B7, NU);

  // ---- fs2 = h1_item @ Ws2 -> B0 ; gat2 (fs=B0, fd=B2) -> B4 (item_infl) ----
  gemm_multi_k<1><<<GEMM_BLOCKS, 256, 0, stream>>>(B6, nullptr, nullptr,
                                                   gat_Wsrc + 2 * W64, gat_bsrc + 2 * B64, B0, NI);
  gat_csr_k<<<EDGE_BLOCKS, 256, 0, stream>>>(B0, B2, gat_attn + 2 * B64, rp_rs, srt_rs, B4, NU);

  // ---- fs3 = h2_user @ Ws3 -> B5 ; gat3 (fs=B5, fd=B3) -> B2 (social_item) ----
  gemm_multi_k<1><<<GEMM_BLOCKS, 256, 0, stream>>>(B7, nullptr, nullptr,
                                                   gat_Wsrc + 3 * W64, gat_bsrc + 3 * B64, B5, NU);
  gat_csr_k<<<EDGE_BLOCKS, 256, 0, stream>>>(B5, B3, gat_attn + 3 * B64, rp_ld, srt_ld, B2, NU);

  // ---- user_pref = [item_infl(B4), social_item(B2)] @ W_out + b_out -> B0 ----
  gemm_multi_k<2><<<GEMM_BLOCKS, 256, 0, stream>>>(B4, B2, nullptr, W_out, b_out, B0, NU);

  // ---- ChebConv(k=3): T1->B5, T2->B3, rst->B6 ----
  dinv_k<<<(NU + 255) / 256, 256, 0, stream>>>(rp_ld, dinv, NU);
  cheb_csr_k<1><<<EDGE_BLOCKS, 256, 0, stream>>>(user_emb, user_emb, nullptr, dinv, lam,
                                                 rp_ld, srt_ld, B5, NU);
  cheb_csr_k<2><<<EDGE_BLOCKS, 256, 0, stream>>>(B5, user_emb, B5, dinv, lam,
                                                 rp_ld, srt_ld, B3, NU);
  gemm_multi_k<3><<<GEMM_BLOCKS, 256, 0, stream>>>(user_emb, B5, B3, cheb_W, cheb_b, B6, NU);

  // ---- rst projections (2-in-1): fs4->B4, fd4->B2 ; gat4 -> B5 (user_social) ----
  proj_k<2><<<GEMM_BLOCKS, 256, 0, stream>>>(
      B6,
      gat_Wsrc + 4 * W64, gat_Wdst + 4 * W64, nullptr, nullptr,
      gat_bsrc + 4 * B64, gat_bdst + 4 * B64, nullptr, nullptr,
      B4, B2, nullptr, nullptr, NU);
  gat_csr_k<<<EDGE_BLOCKS, 256, 0, stream>>>(B4, B2, gat_attn + 4 * B64, rp_ld, srt_ld, B5, NU);

  // ---- mutualistic: h_uP->B4, h_uS->B2 (shared user_emb read) ----
  dual128_k<true><<<DUAL_BLOCKS, 256, 0, stream>>>(
      B0, user_emb, B5, nullptr, Wc, Wsm, bc, bs, B4, B2, NU);
  mut_k<<<(NU + 3) / 4, 256, 0, stream>>>(B4, B2, B3, B7, NU);  // mP->B3, mS->B7
  // h_new_P->B0, h_new_S->B5
  dual128_k<false><<<DUAL_BLOCKS, 256, 0, stream>>>(
      B3, B4, B7, B2, WpP, WpS, bpP, bpS, B0, B5, NU);

  // ---- predictors ----
  float* out = (float*)d_out;
  dot_k<<<EDGE_BLOCKS, 256, 0, stream>>>(B0, item_emb, rate_src, rate_dst, out, NR);
  dot_k<<<EDGE_BLOCKS, 256, 0, stream>>>(B0, item_emb, neg_rate_src, neg_rate_dst, out + NR, NR);
  dot_k<<<EDGE_BLOCKS, 256, 0, stream>>>(B5, user_emb, link_src, link_dst, out + 2 * (size_t)NR, NL);
  dot_k<<<EDGE_BLOCKS, 256, 0, stream>>>(B5, user_emb, neg_link_src, neg_link_dst, out + 2 * (size_t)NR + NL, NL);
}

// Round 10
// 1778.549 us; speedup vs baseline: 1.1611x; 1.1611x over previous
//
#include <hip/hip_runtime.h>

// ---------------------------------------------------------------------------
// MutualRec forward: 5x GATv2 + ChebConv(k=3) + mutualistic MLP + edge dots
// R10: back to R8 scalar-broadcast GEMMs (vector-X R9 regressed). Occupancy
//      fix: GEMM grid 1024->4096 (grid was capping waves at <=50%), proj4
//      split into 2x proj2 (64KB->32KB LDS, 2->5 blocks/CU).
// ---------------------------------------------------------------------------

#define LRELU_SLOPE 0.2f
#define GEMM_BLOCKS 4096
#define DUAL_BLOCKS 1024
#define EDGE_BLOCKS 2048

// ============================ GEMM family ==================================
// Y[N,64] = sum_m X_m[N,64] @ W[m] + b ; W is [NMAT*64,64] row-major stacked.
template <int NMAT>
__global__ void gemm_multi_k(const float* __restrict__ X0,
                             const float* __restrict__ X1,
                             const float* __restrict__ X2,
                             const float* __restrict__ W,
                             const float* __restrict__ b,
                             float* __restrict__ Y, int N) {
  __shared__ float Ws[NMAT * 4096];
  for (int i = threadIdx.x; i < NMAT * 4096; i += 256) Ws[i] = W[i];
  __syncthreads();
  const int lane = threadIdx.x & 63;
  const int gw = (blockIdx.x * 256 + threadIdx.x) >> 6;
  const int nw = (gridDim.x * 256) >> 6;
  const float bj = b[lane];
  for (int r0 = gw * 4; r0 < N; r0 += nw * 4) {
    const int ru = __builtin_amdgcn_readfirstlane(r0);
    const int r1 = (ru + 1 < N) ? ru + 1 : ru;
    const int r2 = (ru + 2 < N) ? ru + 2 : ru;
    const int r3 = (ru + 3 < N) ? ru + 3 : ru;
    float y0 = bj, y1 = bj, y2 = bj, y3 = bj;
#pragma unroll
    for (int m = 0; m < NMAT; ++m) {
      const float* Xm = (m == 0) ? X0 : ((m == 1) ? X1 : X2);
      const float* xr0 = Xm + (size_t)ru * 64;
      const float* xr1 = Xm + (size_t)r1 * 64;
      const float* xr2 = Xm + (size_t)r2 * 64;
      const float* xr3 = Xm + (size_t)r3 * 64;
      const float* wm = Ws + m * 4096;
#pragma unroll 1
      for (int kc = 0; kc < 64; kc += 16) {
#pragma unroll
        for (int kk = 0; kk < 16; ++kk) {
          const int k = kc + kk;
          const float w = wm[k * 64 + lane];
          y0 = fmaf(xr0[k], w, y0);
          y1 = fmaf(xr1[k], w, y1);
          y2 = fmaf(xr2[k], w, y2);
          y3 = fmaf(xr3[k], w, y3);
        }
      }
    }
    Y[(size_t)ru * 64 + lane] = y0;
    if (ru + 1 < N) Y[(size_t)(ru + 1) * 64 + lane] = y1;
    if (ru + 2 < N) Y[(size_t)(ru + 2) * 64 + lane] = y2;
    if (ru + 3 < N) Y[(size_t)(ru + 3) * 64 + lane] = y3;
  }
}

// ---- proj_k<NP>: Y_p = X @ W_p + b_p. One X stream, NP outputs. ----
template <int NP>
__global__ void proj_k(const float* __restrict__ X,
                       const float* __restrict__ W0, const float* __restrict__ W1,
                       const float* __restrict__ W2, const float* __restrict__ W3,
                       const float* __restrict__ b0, const float* __restrict__ b1,
                       const float* __restrict__ b2, const float* __restrict__ b3,
                       float* __restrict__ Y0, float* __restrict__ Y1,
                       float* __restrict__ Y2, float* __restrict__ Y3, int N) {
  __shared__ float Ws[NP * 4096];
#pragma unroll
  for (int p = 0; p < NP; ++p) {
    const float* Wp = (p == 0) ? W0 : ((p == 1) ? W1 : ((p == 2) ? W2 : W3));
    for (int i = threadIdx.x; i < 4096; i += 256) Ws[p * 4096 + i] = Wp[i];
  }
  __syncthreads();
  const int lane = threadIdx.x & 63;
  const int gw = (blockIdx.x * 256 + threadIdx.x) >> 6;
  const int nw = (gridDim.x * 256) >> 6;
  float bj[NP];
#pragma unroll
  for (int p = 0; p < NP; ++p) {
    const float* bp = (p == 0) ? b0 : ((p == 1) ? b1 : ((p == 2) ? b2 : b3));
    bj[p] = bp[lane];
  }
  for (int r0 = gw * 4; r0 < N; r0 += nw * 4) {
    const int ru = __builtin_amdgcn_readfirstlane(r0);
    const int r1 = (ru + 1 < N) ? ru + 1 : ru;
    const int r2 = (ru + 2 < N) ? ru + 2 : ru;
    const int r3 = (ru + 3 < N) ? ru + 3 : ru;
    const float* xr0 = X + (size_t)ru * 64;
    const float* xr1 = X + (size_t)r1 * 64;
    const float* xr2 = X + (size_t)r2 * 64;
    const float* xr3 = X + (size_t)r3 * 64;
    float y[NP][4];
#pragma unroll
    for (int p = 0; p < NP; ++p) {
      y[p][0] = bj[p]; y[p][1] = bj[p]; y[p][2] = bj[p]; y[p][3] = bj[p];
    }
#pragma unroll 1
    for (int kc = 0; kc < 64; kc += 16) {
#pragma unroll
      for (int kk = 0; kk < 16; ++kk) {
        const int k = kc + kk;
        const float x0 = xr0[k], x1 = xr1[k], x2 = xr2[k], x3 = xr3[k];
#pragma unroll
        for (int p = 0; p < NP; ++p) {
          const float w = Ws[p * 4096 + k * 64 + lane];
          y[p][0] = fmaf(x0, w, y[p][0]);
          y[p][1] = fmaf(x1, w, y[p][1]);
          y[p][2] = fmaf(x2, w, y[p][2]);
          y[p][3] = fmaf(x3, w, y[p][3]);
        }
      }
    }
#pragma unroll
    for (int p = 0; p < NP; ++p) {
      float* Yp = (p == 0) ? Y0 : ((p == 1) ? Y1 : ((p == 2) ? Y2 : Y3));
      Yp[(size_t)ru * 64 + lane] = y[p][0];
      if (ru + 1 < N) Yp[(size_t)(ru + 1) * 64 + lane] = y[p][1];
      if (ru + 2 < N) Yp[(size_t)(ru + 2) * 64 + lane] = y[p][2];
      if (ru + 3 < N) Yp[(size_t)(ru + 3) * 64 + lane] = y[p][3];
    }
  }
}

// ---- dual128_k<SHARED>: Y0=[A0,C0]@W0+b0 ; Y1=[A1,C1]@W1+b1 (W: [128,64]).
template <bool SHARED>
__global__ void dual128_k(const float* __restrict__ A0, const float* __restrict__ C0,
                          const float* __restrict__ A1, const float* __restrict__ C1,
                          const float* __restrict__ W0, const float* __restrict__ W1,
                          const float* __restrict__ b0, const float* __restrict__ b1,
                          float* __restrict__ Y0, float* __restrict__ Y1, int N) {
  __shared__ float Ws[2 * 8192];
  for (int i = threadIdx.x; i < 8192; i += 256) Ws[i] = W0[i];
  for (int i = threadIdx.x; i < 8192; i += 256) Ws[8192 + i] = W1[i];
  __syncthreads();
  const int lane = threadIdx.x & 63;
  const int gw = (blockIdx.x * 256 + threadIdx.x) >> 6;
  const int nw = (gridDim.x * 256) >> 6;
  const float bj0 = b0[lane], bj1 = b1[lane];
  for (int r0 = gw * 4; r0 < N; r0 += nw * 4) {
    const int ru = __builtin_amdgcn_readfirstlane(r0);
    const int r1 = (ru + 1 < N) ? ru + 1 : ru;
    const int r2 = (ru + 2 < N) ? ru + 2 : ru;
    const int r3 = (ru + 3 < N) ? ru + 3 : ru;
    float ya[4] = {bj0, bj0, bj0, bj0};
    float yb[4] = {bj1, bj1, bj1, bj1};
    // phase A0 -> ya  (W0 rows 0..63)
    {
      const float* xr0 = A0 + (size_t)ru * 64;
      const float* xr1 = A0 + (size_t)r1 * 64;
      const float* xr2 = A0 + (size_t)r2 * 64;
      const float* xr3 = A0 + (size_t)r3 * 64;
#pragma unroll 1
      for (int kc = 0; kc < 64; kc += 16) {
#pragma unroll
        for (int kk = 0; kk < 16; ++kk) {
          const int k = kc + kk;
          const float w = Ws[k * 64 + lane];
          ya[0] = fmaf(xr0[k], w, ya[0]);
          ya[1] = fmaf(xr1[k], w, ya[1]);
          ya[2] = fmaf(xr2[k], w, ya[2]);
          ya[3] = fmaf(xr3[k], w, ya[3]);
        }
      }
    }
    // phase A1 -> yb  (W1 rows 0..63)
    {
      const float* xr0 = A1 + (size_t)ru * 64;
      const float* xr1 = A1 + (size_t)r1 * 64;
      const float* xr2 = A1 + (size_t)r2 * 64;
      const float* xr3 = A1 + (size_t)r3 * 64;
#pragma unroll 1
      for (int kc = 0; kc < 64; kc += 16) {
#pragma unroll
        for (int kk = 0; kk < 16; ++kk) {
          const int k = kc + kk;
          const float w = Ws[8192 + k * 64 + lane];
          yb[0] = fmaf(xr0[k], w, yb[0]);
          yb[1] = fmaf(xr1[k], w, yb[1]);
          yb[2] = fmaf(xr2[k], w, yb[2]);
          yb[3] = fmaf(xr3[k], w, yb[3]);
        }
      }
    }
    if (SHARED) {
      const float* xr0 = C0 + (size_t)ru * 64;
      const float* xr1 = C0 + (size_t)r1 * 64;
      const float* xr2 = C0 + (size_t)r2 * 64;
      const float* xr3 = C0 + (size_t)r3 * 64;
#pragma unroll 1
      for (int kc = 0; kc < 64; kc += 16) {
#pragma unroll
        for (int kk = 0; kk < 16; ++kk) {
          const int k = kc + kk;
          const float wA = Ws[(64 + k) * 64 + lane];
          const float wB = Ws[8192 + (64 + k) * 64 + lane];
          const float x0 = xr0[k], x1 = xr1[k], x2 = xr2[k], x3 = xr3[k];
          ya[0] = fmaf(x0, wA, ya[0]); yb[0] = fmaf(x0, wB, yb[0]);
          ya[1] = fmaf(x1, wA, ya[1]); yb[1] = fmaf(x1, wB, yb[1]);
          ya[2] = fmaf(x2, wA, ya[2]); yb[2] = fmaf(x2, wB, yb[2]);
          ya[3] = fmaf(x3, wA, ya[3]); yb[3] = fmaf(x3, wB, yb[3]);
        }
      }
    } else {
      {
        const float* xr0 = C0 + (size_t)ru * 64;
        const float* xr1 = C0 + (size_t)r1 * 64;
        const float* xr2 = C0 + (size_t)r2 * 64;
        const float* xr3 = C0 + (size_t)r3 * 64;
#pragma unroll 1
        for (int kc = 0; kc < 64; kc += 16) {
#pragma unroll
          for (int kk = 0; kk < 16; ++kk) {
            const int k = kc + kk;
            const float w = Ws[(64 + k) * 64 + lane];
            ya[0] = fmaf(xr0[k], w, ya[0]);
            ya[1] = fmaf(xr1[k], w, ya[1]);
            ya[2] = fmaf(xr2[k], w, ya[2]);
            ya[3] = fmaf(xr3[k], w, ya[3]);
          }
        }
      }
      {
        const float* xr0 = C1 + (size_t)ru * 64;
        const float* xr1 = C1 + (size_t)r1 * 64;
        const float* xr2 = C1 + (size_t)r2 * 64;
        const float* xr3 = C1 + (size_t)r3 * 64;
#pragma unroll 1
        for (int kc = 0; kc < 64; kc += 16) {
#pragma unroll
          for (int kk = 0; kk < 16; ++kk) {
            const int k = kc + kk;
            const float w = Ws[8192 + (64 + k) * 64 + lane];
            yb[0] = fmaf(xr0[k], w, yb[0]);
            yb[1] = fmaf(xr1[k], w, yb[1]);
            yb[2] = fmaf(xr2[k], w, yb[2]);
            yb[3] = fmaf(xr3[k], w, yb[3]);
          }
        }
      }
    }
    Y0[(size_t)ru * 64 + lane] = ya[0];
    Y1[(size_t)ru * 64 + lane] = yb[0];
    if (ru + 1 < N) { Y0[(size_t)(ru + 1) * 64 + lane] = ya[1]; Y1[(size_t)(ru + 1) * 64 + lane] = yb[1]; }
    if (ru + 2 < N) { Y0[(size_t)(ru + 2) * 64 + lane] = ya[2]; Y1[(size_t)(ru + 2) * 64 + lane] = yb[2]; }
    if (ru + 3 < N) { Y0[(size_t)(ru + 3) * 64 + lane] = ya[3]; Y1[(size_t)(ru + 3) * 64 + lane] = yb[3]; }
  }
}

// ========================= CSR build (counting sort) =======================
__global__ void hist_k(const int* __restrict__ key, int* __restrict__ cnt, int E) {
  const int e = blockIdx.x * blockDim.x + threadIdx.x;
  if (e < E) atomicAdd(cnt + key[e], 1);
}

__global__ void scan1_k(const int* __restrict__ in, int* __restrict__ out,
                        int* __restrict__ bsum, int n) {
  __shared__ int tmp[256];
  const int t = threadIdx.x;
  const int base = blockIdx.x * 1024 + t * 4;
  int v0 = (base + 0 < n) ? in[base + 0] : 0;
  int v1 = (base + 1 < n) ? in[base + 1] : 0;
  int v2 = (base + 2 < n) ? in[base + 2] : 0;
  int v3 = (base + 3 < n) ? in[base + 3] : 0;
  const int s = v0 + v1 + v2 + v3;
  tmp[t] = s;
  __syncthreads();
  for (int off = 1; off < 256; off <<= 1) {
    const int x = (t >= off) ? tmp[t - off] : 0;
    __syncthreads();
    tmp[t] += x;
    __syncthreads();
  }
  const int excl = tmp[t] - s;
  if (t == 255) bsum[blockIdx.x] = tmp[255];
  if (base + 0 < n) out[base + 0] = excl;
  if (base + 1 < n) out[base + 1] = excl + v0;
  if (base + 2 < n) out[base + 2] = excl + v0 + v1;
  if (base + 3 < n) out[base + 3] = excl + v0 + v1 + v2;
}
__global__ void scan2_k(int* __restrict__ bsum, int nb) {
  if (threadIdx.x == 0) {
    int acc = 0;
    for (int i = 0; i < nb; ++i) { const int v = bsum[i]; bsum[i] = acc; acc += v; }
  }
}
__global__ void scan3_k(int* __restrict__ out, const int* __restrict__ bsum, int n) {
  const int i = blockIdx.x * blockDim.x + threadIdx.x;
  if (i < n) out[i] += bsum[i >> 10];
}

__global__ void scatter_k(const int* __restrict__ key, const int* __restrict__ other,
                          int* __restrict__ cursor, int* __restrict__ srt, int E) {
  const int e = blockIdx.x * blockDim.x + threadIdx.x;
  if (e < E) {
    const int p = atomicAdd(cursor + key[e], 1);
    srt[p] = other[e];
  }
}

// ======================= CSR-based graph kernels ===========================
__global__ void gat_csr_k(const float* __restrict__ fs, const float* __restrict__ fd,
                          const float* __restrict__ attn,
                          const int* __restrict__ rowptr, const int* __restrict__ nbr,
                          float* __restrict__ out, int N) {
  const int lane = threadIdx.x & 63;
  const int wid = (blockIdx.x * blockDim.x + threadIdx.x) >> 6;
  const int nw = (gridDim.x * blockDim.x) >> 6;
  const float aw = attn[lane];
  for (int n = wid; n < N; n += nw) {
    const int beg = rowptr[n], end = rowptr[n + 1];
    const float fdv = fd[(size_t)n * 64 + lane];
    float acc = 0.0f, den = 0.0f;
    int e = beg;
    for (; e + 1 < end; e += 2) {
      const int s0 = nbr[e], s1 = nbr[e + 1];
      const float f0 = fs[(size_t)s0 * 64 + lane];
      const float f1 = fs[(size_t)s1 * 64 + lane];
      float v0 = f0 + fdv; v0 = v0 > 0.0f ? v0 : LRELU_SLOPE * v0;
      float v1 = f1 + fdv; v1 = v1 > 0.0f ? v1 : LRELU_SLOPE * v1;
      float p0 = v0 * aw, p1 = v1 * aw;
#pragma unroll
      for (int o = 32; o; o >>= 1) {
        p0 += __shfl_xor(p0, o, 64);
        p1 += __shfl_xor(p1, o, 64);
      }
      const float e0 = __expf(p0), e1 = __expf(p1);
      den += e0 + e1;
      acc = fmaf(e0, f0, acc);
      acc = fmaf(e1, f1, acc);
    }
    if (e < end) {
      const int s0 = nbr[e];
      const float f0 = fs[(size_t)s0 * 64 + lane];
      float v0 = f0 + fdv; v0 = v0 > 0.0f ? v0 : LRELU_SLOPE * v0;
      float p0 = v0 * aw;
#pragma unroll
      for (int o = 32; o; o >>= 1) p0 += __shfl_xor(p0, o, 64);
      const float e0 = __expf(p0);
      den += e0;
      acc = fmaf(e0, f0, acc);
    }
    const float inv = den > 0.0f ? 1.0f / den : 0.0f;
    out[(size_t)n * 64 + lane] = acc * inv;
  }
}

// Fused Cheb step (MODE 1: T1; MODE 2: T2)
template <int MODE>
__global__ void cheb_csr_k(const float* __restrict__ x, const float* __restrict__ T0,
                           const float* __restrict__ Tp, const float* __restrict__ dinv,
                           const float* __restrict__ lam,
                           const int* __restrict__ rowptr, const int* __restrict__ nbr,
                           float* __restrict__ outT, int N) {
  const float re = 2.0f / lam[0];
  const int lane = threadIdx.x & 63;
  const int wid = (blockIdx.x * blockDim.x + threadIdx.x) >> 6;
  const int nw = (gridDim.x * blockDim.x) >> 6;
  for (int n = wid; n < N; n += nw) {
    const int beg = rowptr[n], end = rowptr[n + 1];
    float acc = 0.0f;
    int e = beg;
    for (; e + 1 < end; e += 2) {
      const int s0 = nbr[e], s1 = nbr[e + 1];
      acc = fmaf(x[(size_t)s0 * 64 + lane], dinv[s0], acc);
      acc = fmaf(x[(size_t)s1 * 64 + lane], dinv[s1], acc);
    }
    if (e < end) {
      const int s0 = nbr[e];
      acc = fmaf(x[(size_t)s0 * 64 + lane], dinv[s0], acc);
    }
    const float hv = acc * dinv[n];
    float r;
    if (MODE == 1) {
      r = -re * hv + (re - 1.0f) * T0[(size_t)n * 64 + lane];
    } else {
      r = -2.0f * re * hv + 2.0f * (re - 1.0f) * Tp[(size_t)n * 64 + lane]
          - T0[(size_t)n * 64 + lane];
    }
    outT[(size_t)n * 64 + lane] = r;
  }
}

__global__ void dinv_k(const int* __restrict__ rowptr, float* __restrict__ dinv, int N) {
  const int i = blockIdx.x * blockDim.x + threadIdx.x;
  if (i < N) {
    const float deg = (float)(rowptr[i + 1] - rowptr[i]);
    dinv[i] = rsqrtf(fmaxf(deg, 1.0f));
  }
}

// ---- mutualistic ----
__global__ void mut_k(const float* __restrict__ hP, const float* __restrict__ hS,
                      float* __restrict__ mP, float* __restrict__ mS, int N) {
  const int lane = threadIdx.x & 63;
  const int u = (blockIdx.x * blockDim.x + threadIdx.x) >> 6;
  if (u >= N) return;
  const float p = hP[(size_t)u * 64 + lane];
  const float s = hS[(size_t)u * 64 + lane];
  const float m = p * s;
  float mxp = p, mxs = s;
#pragma unroll
  for (int o = 32; o; o >>= 1) {
    mxp = fmaxf(mxp, __shfl_xor(mxp, o, 64));
    mxs = fmaxf(mxs, __shfl_xor(mxs, o, 64));
  }
  const float ep = __expf(p - mxp);
  const float es = __expf(s - mxs);
  float sp = ep, ss = es;
#pragma unroll
  for (int o = 32; o; o >>= 1) {
    sp += __shfl_xor(sp, o, 64);
    ss += __shfl_xor(ss, o, 64);
  }
  mP[(size_t)u * 64 + lane] = m * (ep / sp);
  mS[(size_t)u * 64 + lane] = m * (es / ss);
}

// ---- edge dot (edge-list, ILP-2) ----
__global__ void dot_k(const float* __restrict__ A, const float* __restrict__ Bm,
                      const int* __restrict__ src, const int* __restrict__ dst,
                      float* __restrict__ out, int E) {
  const int lane = threadIdx.x & 63;
  const int wid = (blockIdx.x * blockDim.x + threadIdx.x) >> 6;
  const int nw = (gridDim.x * blockDim.x) >> 6;
  for (int e0 = wid * 2; e0 < E; e0 += nw * 2) {
    const bool has1 = (e0 + 1 < E);
    const int s0 = src[e0], d0 = dst[e0];
    const int s1 = has1 ? src[e0 + 1] : s0;
    const int d1 = has1 ? dst[e0 + 1] : d0;
    float p0 = A[(size_t)s0 * 64 + lane] * Bm[(size_t)d0 * 64 + lane];
    float p1 = A[(size_t)s1 * 64 + lane] * Bm[(size_t)d1 * 64 + lane];
#pragma unroll
    for (int o = 32; o; o >>= 1) {
      p0 += __shfl_xor(p0, o, 64);
      p1 += __shfl_xor(p1, o, 64);
    }
    if (lane == 0) {
      out[e0] = p0;
      if (has1) out[e0 + 1] = p1;
    }
  }
}

// ---------------------------------------------------------------------------

static void build_csr(const int* key, const int* other, int E, int N,
                      int* rowptr, int* srt, int* cursor, int* bsum,
                      hipStream_t stream) {
  const int n1 = N + 1;
  hipMemsetAsync(cursor, 0, (size_t)n1 * 4, stream);
  hist_k<<<(E + 255) / 256, 256, 0, stream>>>(key, cursor, E);
  const int nb = (n1 + 1023) / 1024;
  scan1_k<<<nb, 256, 0, stream>>>(cursor, rowptr, bsum, n1);
  scan2_k<<<1, 64, 0, stream>>>(bsum, nb);
  scan3_k<<<(n1 + 255) / 256, 256, 0, stream>>>(rowptr, bsum, n1);
  hipMemcpyAsync(cursor, rowptr, (size_t)N * 4, hipMemcpyDeviceToDevice, stream);
  scatter_k<<<(E + 255) / 256, 256, 0, stream>>>(key, other, cursor, srt, E);
}

extern "C" void kernel_launch(void* const* d_in, const int* in_sizes, int n_in,
                              void* d_out, int out_size, void* d_ws, size_t ws_size,
                              hipStream_t stream) {
  const float* user_emb = (const float*)d_in[0];
  const float* item_emb = (const float*)d_in[1];
  const int* rate_src = (const int*)d_in[2];
  const int* rate_dst = (const int*)d_in[3];
  const int* link_src = (const int*)d_in[4];
  const int* link_dst = (const int*)d_in[5];
  const int* neg_rate_src = (const int*)d_in[6];
  const int* neg_rate_dst = (const int*)d_in[7];
  const int* neg_link_src = (const int*)d_in[8];
  const int* neg_link_dst = (const int*)d_in[9];
  const float* lam = (const float*)d_in[10];
  const float* gat_Wsrc = (const float*)d_in[11];
  const float* gat_bsrc = (const float*)d_in[12];
  const float* gat_Wdst = (const float*)d_in[13];
  const float* gat_bdst = (const float*)d_in[14];
  const float* gat_attn = (const float*)d_in[15];
  const float* W_out = (const float*)d_in[16];
  const float* b_out = (const float*)d_in[17];
  const float* cheb_W = (const float*)d_in[18];
  const float* cheb_b = (const float*)d_in[19];
  const float* Wc = (const float*)d_in[20];
  const float* bc = (const float*)d_in[21];
  const float* Wsm = (const float*)d_in[22];
  const float* bs = (const float*)d_in[23];
  const float* WpP = (const float*)d_in[24];
  const float* bpP = (const float*)d_in[25];
  const float* WpS = (const float*)d_in[26];
  const float* bpS = (const float*)d_in[27];

  const int NU = in_sizes[0] / 64;
  const int NI = in_sizes[1] / 64;
  const int NR = in_sizes[2];
  const int NL = in_sizes[4];
  const int NMAX = NU > NI ? NU : NI;
  const size_t MAT = (size_t)NMAX * 64;

  float* ws = (float*)d_ws;
  float* B0 = ws + 0 * MAT;
  float* B1 = ws + 1 * MAT;
  float* B2 = ws + 2 * MAT;
  float* B3 = ws + 3 * MAT;
  float* B4 = ws + 4 * MAT;
  float* B5 = ws + 5 * MAT;
  float* B6 = ws + 6 * MAT;
  float* B7 = ws + 7 * MAT;
  int* ip = (int*)(ws + 8 * MAT);
  int* rp_rd = ip;                   // NI+1
  int* rp_rs = rp_rd + (NI + 1);     // NU+1
  int* rp_ld = rp_rs + (NU + 1);     // NU+1
  int* srt_rd = rp_ld + (NU + 1);    // NR
  int* srt_rs = srt_rd + NR;         // NR
  int* srt_ld = srt_rs + NR;         // NL
  int* cursor = srt_ld + NL;         // NMAX+1
  int* bsum = cursor + (NMAX + 1);   // 256
  float* dinv = (float*)(bsum + 256);  // NU

  const int W64 = 64 * 64, B64 = 64;

  // ---- 3 CSR groupings ----
  build_csr(rate_dst, rate_src, NR, NI, rp_rd, srt_rd, cursor, bsum, stream);
  build_csr(rate_src, rate_dst, NR, NU, rp_rs, srt_rs, cursor, bsum, stream);
  build_csr(link_dst, link_src, NL, NU, rp_ld, srt_ld, cursor, bsum, stream);

  // ---- user projections (2x proj2): fs0->B0, fd1->B1 ; fd2->B2, fd3->B3 ----
  proj_k<2><<<GEMM_BLOCKS, 256, 0, stream>>>(
      user_emb,
      gat_Wsrc + 0 * W64, gat_Wdst + 1 * W64, nullptr, nullptr,
      gat_bsrc + 0 * B64, gat_bdst + 1 * B64, nullptr, nullptr,
      B0, B1, nullptr, nullptr, NU);
  proj_k<2><<<GEMM_BLOCKS, 256, 0, stream>>>(
      user_emb,
      gat_Wdst + 2 * W64, gat_Wdst + 3 * W64, nullptr, nullptr,
      gat_bdst + 2 * B64, gat_bdst + 3 * B64, nullptr, nullptr,
      B2, B3, nullptr, nullptr, NU);
  // ---- item projections (2-in-1): fd0->B4, fs1->B5 ----
  proj_k<2><<<GEMM_BLOCKS, 256, 0, stream>>>(
      item_emb,
      gat_Wdst + 0 * W64, gat_Wsrc + 1 * W64, nullptr, nullptr,
      gat_bdst + 0 * B64, gat_bsrc + 1 * B64, nullptr, nullptr,
      B4, B5, nullptr, nullptr, NI);

  // ---- gat0: (fs=B0, fd=B4) over rate-by-item -> B6 (h1_item) ----
  gat_csr_k<<<EDGE_BLOCKS, 256, 0, stream>>>(B0, B4, gat_attn + 0 * B64, rp_rd, srt_rd, B6, NI);
  // ---- gat1: (fs=B5, fd=B1) over rate-by-user -> B7 (h2_user) ----
  gat_csr_k<<<EDGE_BLOCKS, 256, 0, stream>>>(B5, B1, gat_attn + 1 * B64, rp_rs, srt_rs, B7, NU);

  // ---- fs2 = h1_item @ Ws2 -> B0 ; gat2 (fs=B0, fd=B2) -> B4 (item_infl) ----
  gemm_multi_k<1><<<GEMM_BLOCKS, 256, 0, stream>>>(B6, nullptr, nullptr,
                                                   gat_Wsrc + 2 * W64, gat_bsrc + 2 * B64, B0, NI);
  gat_csr_k<<<EDGE_BLOCKS, 256, 0, stream>>>(B0, B2, gat_attn + 2 * B64, rp_rs, srt_rs, B4, NU);

  // ---- fs3 = h2_user @ Ws3 -> B5 ; gat3 (fs=B5, fd=B3) -> B2 (social_item) ----
  gemm_multi_k<1><<<GEMM_BLOCKS, 256, 0, stream>>>(B7, nullptr, nullptr,
                                                   gat_Wsrc + 3 * W64, gat_bsrc + 3 * B64, B5, NU);
  gat_csr_k<<<EDGE_BLOCKS, 256, 0, stream>>>(B5, B3, gat_attn + 3 * B64, rp_ld, srt_ld, B2, NU);

  // ---- user_pref = [item_infl(B4), social_item(B2)] @ W_out + b_out -> B0 ----
  gemm_multi_k<2><<<GEMM_BLOCKS, 256, 0, stream>>>(B4, B2, nullptr, W_out, b_out, B0, NU);

  // ---- ChebConv(k=3): T1->B5, T2->B3, rst->B6 ----
  dinv_k<<<(NU + 255) / 256, 256, 0, stream>>>(rp_ld, dinv, NU);
  cheb_csr_k<1><<<EDGE_BLOCKS, 256, 0, stream>>>(user_emb, user_emb, nullptr, dinv, lam,
                                                 rp_ld, srt_ld, B5, NU);
  cheb_csr_k<2><<<EDGE_BLOCKS, 256, 0, stream>>>(B5, user_emb, B5, dinv, lam,
                                                 rp_ld, srt_ld, B3, NU);
  gemm_multi_k<3><<<GEMM_BLOCKS, 256, 0, stream>>>(user_emb, B5, B3, cheb_W, cheb_b, B6, NU);

  // ---- rst projections (2-in-1): fs4->B4, fd4->B2 ; gat4 -> B5 (user_social) ----
  proj_k<2><<<GEMM_BLOCKS, 256, 0, stream>>>(
      B6,
      gat_Wsrc + 4 * W64, gat_Wdst + 4 * W64, nullptr, nullptr,
      gat_bsrc + 4 * B64, gat_bdst + 4 * B64, nullptr, nullptr,
      B4, B2, nullptr, nullptr, NU);
  gat_csr_k<<<EDGE_BLOCKS, 256, 0, stream>>>(B4, B2, gat_attn + 4 * B64, rp_ld, srt_ld, B5, NU);

  // ---- mutualistic: h_uP->B4, h_uS->B2 (shared user_emb read) ----
  dual128_k<true><<<DUAL_BLOCKS, 256, 0, stream>>>(
      B0, user_emb, B5, nullptr, Wc, Wsm, bc, bs, B4, B2, NU);
  mut_k<<<(NU + 3) / 4, 256, 0, stream>>>(B4, B2, B3, B7, NU);  // mP->B3, mS->B7
  // h_new_P->B0, h_new_S->B5
  dual128_k<false><<<DUAL_BLOCKS, 256, 0, stream>>>(
      B3, B4, B7, B2, WpP, WpS, bpP, bpS, B0, B5, NU);

  // ---- predictors ----
  float* out = (float*)d_out;
  dot_k<<<EDGE_BLOCKS, 256, 0, stream>>>(B0, item_emb, rate_src, rate_dst, out, NR);
  dot_k<<<EDGE_BLOCKS, 256, 0, stream>>>(B0, item_emb, neg_rate_src, neg_rate_dst, out + NR, NR);
  dot_k<<<EDGE_BLOCKS, 256, 0, stream>>>(B5, user_emb, link_src, link_dst, out + 2 * (size_t)NR, NL);
  dot_k<<<EDGE_BLOCKS, 256, 0, stream>>>(B5, user_emb, neg_link_src, neg_link_dst, out + 2 * (size_t)NR + NL, NL);
}